// Round 4
// baseline (889.491 us; speedup 1.0000x reference)
//
#include <hip/hip_runtime.h>
#include <stdint.h>

#define OBS_LEN 12
#define KS 20
#define BB 2048
#define HD 128
#define MIDD 256
#define NCQ 2

using f32x4  = __attribute__((ext_vector_type(4))) float;
using bf16x8 = __attribute__((ext_vector_type(8))) short;

static __device__ __forceinline__ short f2bf(float f){
  return __builtin_bit_cast(short, (__bf16)f);   // RNE convert
}
static __device__ __forceinline__ uint32_t pack2(float a, float b){
  return (uint32_t)(uint16_t)f2bf(a) | ((uint32_t)(uint16_t)f2bf(b) << 16);
}
static __device__ __forceinline__ float hsig(float x){
  return fminf(fmaxf(fmaf(x, 0.16666666666666666f, 0.5f), 0.f), 1.f);
}
static __device__ __forceinline__ float clip1(float x){
  return fminf(fmaxf(x, -1.f), 1.f);
}
static __device__ __forceinline__ f32x4 mm(bf16x8 a, bf16x8 b, f32x4 c){
  return __builtin_amdgcn_mfma_f32_16x16x32_bf16(a, b, c, 0, 0, 0);
}
static __device__ __forceinline__ bf16x8 ldh(const uint16_t* buf, int row, int q, int p){
  return *reinterpret_cast<const bf16x8*>(&buf[(row*HD + q*32 + p*8) ^ ((row&7)*8)]);
}
static __device__ __forceinline__ bf16x8 lda(const uint16_t* buf, int row, int q, int p){
  return *reinterpret_cast<const bf16x8*>(&buf[(row*MIDD + q*32 + p*8) ^ ((row&7)*8)]);
}
// scalar-extract a B-fragment from a swizzled [NR][NCOLS] bf16 LDS tile.
// rbase must be a multiple of 8 so (r&7)==j matches the write-side swizzle.
template<int NCOLS>
static __device__ __forceinline__ bf16x8 fragw(const uint16_t* ws, int rbase, int col){
  bf16x8 wf;
  #pragma unroll
  for (int j=0;j<8;++j){
    wf[j] = (short)ws[((rbase+j)*NCOLS + col) ^ (j*8)];
  }
  return wf;
}
// stage 16384 fp32 elements ([NR][NCOLS]) as swizzled bf16 into dst (512 threads)
template<int NCOLS>
static __device__ __forceinline__ void stage_w(const float* __restrict__ src,
                                               uint16_t* dst, int tid){
  #pragma unroll
  for (int it=0; it<8; ++it){
    int u = tid + it*512;
    int row, c4;
    if constexpr (NCOLS == 128){ row = u>>5; c4 = (u&31)*4; }
    else                       { row = u>>6; c4 = (u&63)*4; }
    float4 v = *reinterpret_cast<const float4*>(src + row*NCOLS + c4);
    int e = (row*NCOLS + c4) ^ ((row&7)*8);
    *reinterpret_cast<uint32_t*>(&dst[e])   = pack2(v.x, v.y);
    *reinterpret_cast<uint32_t*>(&dst[e+2]) = pack2(v.z, v.w);
  }
}
// stage 32x128 fp32 -> swizzled bf16 (256 threads of one group; lt in [0,256))
static __device__ __forceinline__ void stage_h(const float* __restrict__ src,
                                               uint16_t* dst, int lt){
  #pragma unroll
  for (int it=0; it<4; ++it){
    int u = lt + it*256;
    int row = u >> 5, c4 = (u & 31)*4;
    float4 v = *reinterpret_cast<const float4*>(src + row*HD + c4);
    int e = (row*HD + c4) ^ ((row&7)*8);
    *reinterpret_cast<uint32_t*>(&dst[e])   = pack2(v.x, v.y);
    *reinterpret_cast<uint32_t*>(&dst[e+2]) = pack2(v.z, v.w);
  }
}

__global__ __launch_bounds__(512, 1)
void CRMF_35296041239144_kernel(
    const float* __restrict__ obs,  const float* __restrict__ pred,
    const float* __restrict__ mw0,  const float* __restrict__ mb0,
    const float* __restrict__ mw1,  const float* __restrict__ mb1,
    const float* __restrict__ wih,  const float* __restrict__ whh,
    const float* __restrict__ bih,  const float* __restrict__ bhh,
    const float* __restrict__ oww,  const float* __restrict__ obb,
    float* __restrict__ outp)
{
  __shared__ __align__(16) uint16_t wstage[16384];       // 32 KB weight staging (shared)
  __shared__ __align__(16) uint16_t hbufg[2][32*HD];     // 2 x 8 KB h-state (per group)
  __shared__ __align__(16) uint16_t abufg[2][32*MIDD];   // 2 x 16 KB MLP acts (per group)
  __shared__ float2 xbuf[OBS_LEN][32];                   // shared (same b0)

  const int tid = threadIdx.x;
  const int g   = tid >> 8;          // wave-group 0/1
  const int lt  = tid & 255;
  const int w   = lt >> 6;           // wave-in-group 0..3
  const int p   = (tid >> 4) & 3;
  const int ln  = tid & 15;
  const int wofs = w * 32;
  const bool wOut = (w == (g ? 0 : 3));   // out-proj wave; balanced across SIMDs

  const int b     = blockIdx.x;      // 256 blocks, persistent, 1/CU
  const int b0    = (b & 63) * 32;
  const int kslot = b >> 6;          // 0..3

  uint16_t* hb = hbufg[g];
  uint16_t* ab = abufg[g];

  // ---- shifted obs ----
  for (int u = tid; u < OBS_LEN*32; u += 512){
    int t = u >> 5, cc = u & 31;
    int st = t ? (t-1) : 0;
    const float* pp = obs + ((size_t)st*BB + b0 + cc)*3;
    xbuf[t][cc] = make_float2(pp[0], pp[1]);
  }

  // ---- whh -> register fragments via coalesced LDS staging (once per block) ----
  bf16x8 wfrag[8][4];
  #pragma unroll
  for (int g4=0; g4<4; ++g4){        // one 128-row piece per gate
    if (g4) __syncthreads();         // WAR on wstage
    stage_w<128>(whh + (size_t)g4*128*HD, wstage, tid);
    __syncthreads();
    #pragma unroll
    for (int hf=0; hf<2; ++hf){
      int r = wofs + hf*16 + ln;
      #pragma unroll
      for (int q=0; q<4; ++q)
        wfrag[g4*2+hf][q] = ldh(wstage, r, q, p);
    }
  }

  // ---- small scattered loads (once per block) ----
  float wihA[8], wihB[8], biasv[8];
  #pragma unroll
  for (int ct=0; ct<8; ++ct){
    int col = (ct>>1)*128 + wofs + (ct&1)*16 + ln;
    wihA[ct]  = wih[col*2];
    wihB[ct]  = wih[col*2+1];
    biasv[ct] = bih[col] + bhh[col];
  }
  bf16x8 wfragO[4];
  float obv = 0.f;
  if (wOut){
    #pragma unroll
    for (int q=0; q<4; ++q){
      bf16x8 wf;
      #pragma unroll
      for (int j=0; j<8; ++j){
        int k = q*32 + p*8 + j;
        wf[j] = (ln < NCQ) ? f2bf(oww[k*NCQ + ln]) : (short)0;
      }
      wfragO[q] = wf;
    }
    if (ln < NCQ) obv = obb[ln];
  }

  // ---- 3 iterations: group0 does chunks {0,1,2}, group1 {3,4, redo-3} ----
  #pragma unroll 1
  for (int i=0; i<3; ++i){
    const int c  = g ? ((i==2) ? 3 : 3+i) : i;   // idle slot harmlessly redoes c=3
    const int kk = kslot + 4*c;

    __syncthreads();                 // WAR: hb readers + wstage readers done
    stage_h(pred + ((size_t)(kk*BB + b0))*HD, hb, lt);

    // ---- MLP GEMM1: [32,128] @ map_w0 -> [32,256], leaky_relu ----
    f32x4 acc1[2][4];
    #pragma unroll
    for (int ct=0; ct<4; ++ct){
      float mb = mb0[wofs*2 + ct*16 + ln];
      f32x4 v = {mb,mb,mb,mb};
      acc1[0][ct] = v; acc1[1][ct] = v;
    }
    #pragma unroll 1
    for (int hk=0; hk<2; ++hk){
      if (hk) __syncthreads();       // WAR on wstage
      stage_w<256>(mw0 + (size_t)hk*64*MIDD, wstage, tid);
      __syncthreads();               // wstage (and hb at hk==0) ready
      #pragma unroll
      for (int qq=0; qq<2; ++qq){
        int q = hk*2 + qq;
        bf16x8 af0 = ldh(hb, ln, q, p), af1 = ldh(hb, 16+ln, q, p);
        int rbase = qq*32 + p*8;
        #pragma unroll
        for (int ct=0; ct<4; ++ct){
          bf16x8 wf = fragw<256>(wstage, rbase, wofs*2 + ct*16 + ln);
          acc1[0][ct] = mm(af0, wf, acc1[0][ct]);
          acc1[1][ct] = mm(af1, wf, acc1[1][ct]);
        }
      }
    }
    #pragma unroll
    for (int rt=0; rt<2; ++rt)
    #pragma unroll
    for (int ct=0; ct<4; ++ct)
    #pragma unroll
    for (int r=0; r<4; ++r){
      float v = acc1[rt][ct][r];
      v = (v > 0.f) ? v : 0.01f*v;
      int row = rt*16 + p*4 + r;
      ab[(row*MIDD + wofs*2 + ct*16 + ln) ^ ((row&7)*8)] = (uint16_t)f2bf(v);
    }
    __syncthreads();                 // ab ready; GEMM1 wstage reads done

    // ---- MLP GEMM2: [32,256] @ map_w1 -> h_init [32,128] ----
    f32x4 acc2[2][2];
    #pragma unroll
    for (int d=0; d<2; ++d){
      float mb = mb1[wofs + d*16 + ln];
      f32x4 v = {mb,mb,mb,mb};
      acc2[0][d] = v; acc2[1][d] = v;
    }
    #pragma unroll 1
    for (int hk=0; hk<2; ++hk){
      if (hk) __syncthreads();
      stage_w<128>(mw1 + (size_t)hk*128*HD, wstage, tid);
      __syncthreads();
      #pragma unroll
      for (int qq=0; qq<4; ++qq){
        int q = hk*4 + qq;
        bf16x8 af0 = lda(ab, ln, q, p), af1 = lda(ab, 16+ln, q, p);
        int rbase = qq*32 + p*8;
        #pragma unroll
        for (int d=0; d<2; ++d){
          bf16x8 wf = fragw<128>(wstage, rbase, wofs + d*16 + ln);
          acc2[0][d] = mm(af0, wf, acc2[0][d]);
          acc2[1][d] = mm(af1, wf, acc2[1][d]);
        }
      }
    }
    float c_[2][2][4];
    #pragma unroll
    for (int rt=0; rt<2; ++rt)
    #pragma unroll
    for (int d=0; d<2; ++d)
    #pragma unroll
    for (int r=0; r<4; ++r){
      int row = rt*16 + p*4 + r;
      hb[(row*HD + wofs + d*16 + ln) ^ ((row&7)*8)] = (uint16_t)f2bf(acc2[rt][d][r]);
      c_[rt][d][r] = 0.f;
    }
    __syncthreads();                 // h_init visible

    // ---- 12 recurrent steps (single h-buffer: read phase | barrier | write phase) ----
    f32x4 acc[2][8];
    f32x4 acc8[2];
    for (int t=0; t<OBS_LEN; ++t){
      // C-init = x@w_ih^T + (b_ih+b_hh)
      #pragma unroll
      for (int rt=0; rt<2; ++rt){
        float2 xv[4];
        #pragma unroll
        for (int r=0; r<4; ++r) xv[r] = xbuf[t][rt*16 + p*4 + r];
        #pragma unroll
        for (int ct=0; ct<8; ++ct){
          f32x4 a;
          #pragma unroll
          for (int r=0; r<4; ++r)
            a[r] = fmaf(xv[r].x, wihA[ct], fmaf(xv[r].y, wihB[ct], biasv[ct]));
          acc[rt][ct] = a;
        }
      }
      if (wOut){ f32x4 v = {obv,obv,obv,obv}; acc8[0] = v; acc8[1] = v; }
      #pragma unroll
      for (int q=0; q<4; ++q){
        bf16x8 af0 = ldh(hb, ln, q, p), af1 = ldh(hb, 16+ln, q, p);
        #pragma unroll
        for (int ct=0; ct<8; ++ct){
          acc[0][ct] = mm(af0, wfrag[ct][q], acc[0][ct]);
          acc[1][ct] = mm(af1, wfrag[ct][q], acc[1][ct]);
        }
        if (wOut){
          acc8[0] = mm(af0, wfragO[q], acc8[0]);
          acc8[1] = mm(af1, wfragO[q], acc8[1]);
        }
      }
      if (wOut && t > 0 && ln < NCQ){
        #pragma unroll
        for (int rt=0; rt<2; ++rt)
        #pragma unroll
        for (int r=0; r<4; ++r){
          int cell = rt*16 + p*4 + r;
          outp[(((size_t)(t-1)*KS + kk)*BB + b0 + cell)*NCQ + ln] = acc8[rt][r];
        }
      }
      __syncthreads();               // all reads of hb done
      #pragma unroll
      for (int rt=0; rt<2; ++rt)
      #pragma unroll
      for (int d=0; d<2; ++d)
      #pragma unroll
      for (int r=0; r<4; ++r){
        float iv = hsig(acc[rt][0+d][r]);
        float fv = hsig(acc[rt][2+d][r]);
        float gv = clip1(acc[rt][4+d][r]);
        float ov = hsig(acc[rt][6+d][r]);
        float cv = fmaf(fv, c_[rt][d][r], iv*gv);
        c_[rt][d][r] = cv;
        float hv = ov * clip1(cv);
        int row = rt*16 + p*4 + r;
        hb[(row*HD + wofs + d*16 + ln) ^ ((row&7)*8)] = (uint16_t)f2bf(hv);
      }
      __syncthreads();               // new h visible
    }

    // ---- final output out_11 = h_11 @ out_w + out_b ----
    if (wOut){
      f32x4 o0 = {obv,obv,obv,obv}; f32x4 o1 = o0;
      #pragma unroll
      for (int q=0; q<4; ++q){
        bf16x8 af0 = ldh(hb, ln, q, p), af1 = ldh(hb, 16+ln, q, p);
        o0 = mm(af0, wfragO[q], o0);
        o1 = mm(af1, wfragO[q], o1);
      }
      if (ln < NCQ){
        #pragma unroll
        for (int r=0; r<4; ++r){
          outp[(((size_t)11*KS + kk)*BB + b0 +      (p*4 + r))*NCQ + ln] = o0[r];
          outp[(((size_t)11*KS + kk)*BB + b0 + 16 + (p*4 + r))*NCQ + ln] = o1[r];
        }
      }
    }
  }
}

extern "C" void kernel_launch(void* const* d_in, const int* in_sizes, int n_in,
                              void* d_out, int out_size, void* d_ws, size_t ws_size,
                              hipStream_t stream) {
  (void)in_sizes; (void)n_in; (void)d_ws; (void)ws_size; (void)out_size;
  CRMF_35296041239144_kernel<<<dim3(256), dim3(512), 0, stream>>>(
      (const float*)d_in[0], (const float*)d_in[1], (const float*)d_in[2],
      (const float*)d_in[3], (const float*)d_in[4], (const float*)d_in[5],
      (const float*)d_in[6], (const float*)d_in[7], (const float*)d_in[8],
      (const float*)d_in[9], (const float*)d_in[10], (const float*)d_in[11],
      (float*)d_out);
}

// Round 5
// 171.186 us; speedup vs baseline: 5.1960x; 5.1960x over previous
//
#include <hip/hip_runtime.h>
#include <stdint.h>

#define OBS_LEN 12
#define KS 20
#define BB 2048
#define HD 128
#define MIDD 256
#define NCQ 2

using f32x4  = __attribute__((ext_vector_type(4))) float;
using bf16x8 = __attribute__((ext_vector_type(8))) short;

static __device__ __forceinline__ short f2bf(float f){
  return __builtin_bit_cast(short, (__bf16)f);   // RNE convert
}
static __device__ __forceinline__ uint32_t pack2(float a, float b){
  return (uint32_t)(uint16_t)f2bf(a) | ((uint32_t)(uint16_t)f2bf(b) << 16);
}
static __device__ __forceinline__ float hsig(float x){
  return fminf(fmaxf(fmaf(x, 0.16666666666666666f, 0.5f), 0.f), 1.f);
}
static __device__ __forceinline__ float clip1(float x){
  return fminf(fmaxf(x, -1.f), 1.f);
}
static __device__ __forceinline__ f32x4 mm(bf16x8 a, bf16x8 b, f32x4 c){
  return __builtin_amdgcn_mfma_f32_16x16x32_bf16(a, b, c, 0, 0, 0);
}
static __device__ __forceinline__ bf16x8 ldh(const uint16_t* buf, int row, int q, int p){
  return *reinterpret_cast<const bf16x8*>(&buf[(row*HD + q*32 + p*8) ^ ((row&7)*8)]);
}
static __device__ __forceinline__ bf16x8 lda(const uint16_t* buf, int row, int q, int p){
  return *reinterpret_cast<const bf16x8*>(&buf[(row*MIDD + q*32 + p*8) ^ ((row&7)*8)]);
}

__global__ __launch_bounds__(512, 2)
void CRMF_35296041239144_kernel(
    const float* __restrict__ obs,  const float* __restrict__ pred,
    const float* __restrict__ mw0,  const float* __restrict__ mb0,
    const float* __restrict__ mw1,  const float* __restrict__ mb1,
    const float* __restrict__ wih,  const float* __restrict__ whh,
    const float* __restrict__ bih,  const float* __restrict__ bhh,
    const float* __restrict__ oww,  const float* __restrict__ obb,
    float* __restrict__ outp)
{
  __shared__ __align__(16) uint16_t hbuf[32*HD];     // 8 KB h-state (swizzled bf16)
  __shared__ __align__(16) uint16_t abuf[32*MIDD];   // 16 KB MLP activations
  __shared__ __align__(16) uint16_t ofrag[4*64*8];   // 4 KB out_w B-fragments
  __shared__ float2 xbuf[OBS_LEN][32];               // 3 KB shifted obs

  const int tid = threadIdx.x;
  const int w   = tid >> 6;          // wave 0..7
  const int l   = tid & 63;
  const int p   = (tid >> 4) & 3;
  const int ln  = tid & 15;
  const int wofs = w * 16;           // this wave's 16-hd slice
  const bool w7 = (w == 7);

  const int b     = blockIdx.x;      // 256 blocks, 1 per CU
  const int b0    = (b & 63) * 32;
  const int kslot = b >> 6;          // kk = kslot*5 + c

  // ---- shifted obs ----
  if (tid < OBS_LEN*32){
    int t = tid >> 5, cc = tid & 31;
    int st = t ? (t-1) : 0;
    const float* pp = obs + ((size_t)st*BB + b0 + cc)*3;
    xbuf[t][cc] = make_float2(pp[0], pp[1]);
  }
  // ---- out_w fragments -> LDS (so they never occupy registers) ----
  if (w == 0){
    #pragma unroll
    for (int q=0; q<4; ++q){
      bf16x8 wf;
      #pragma unroll
      for (int j=0; j<8; ++j){
        int k = q*32 + p*8 + j;
        wf[j] = (ln < NCQ) ? f2bf(oww[k*NCQ + ln]) : (short)0;
      }
      *reinterpret_cast<bf16x8*>(&ofrag[(q*64 + l)*8]) = wf;
    }
  }
  const float obv = (ln < NCQ) ? obb[ln] : 0.f;

  // ---- w_hh -> register fragments: 16 cols x 4 gates per wave (64 VGPR) ----
  bf16x8 wfrag[4][4];
  float wihA[4], wihB[4], biasv[4];
  #pragma unroll
  for (int gate=0; gate<4; ++gate){
    int col = gate*128 + wofs + ln;
    wihA[gate]  = wih[col*2];
    wihB[gate]  = wih[col*2+1];
    biasv[gate] = bih[col] + bhh[col];
    #pragma unroll
    for (int q=0; q<4; ++q){
      const float* s = whh + col*HD + q*32 + p*8;
      float4 f0 = *reinterpret_cast<const float4*>(s);
      float4 f1 = *reinterpret_cast<const float4*>(s+4);
      bf16x8 wf;
      wf[0]=f2bf(f0.x); wf[1]=f2bf(f0.y); wf[2]=f2bf(f0.z); wf[3]=f2bf(f0.w);
      wf[4]=f2bf(f1.x); wf[5]=f2bf(f1.y); wf[6]=f2bf(f1.z); wf[7]=f2bf(f1.w);
      wfrag[gate][q] = wf;
    }
  }

  // ---- 5 sequential chunks per block ----
  #pragma unroll 1
  for (int c=0; c<5; ++c){
    const int kk = kslot*5 + c;

    __syncthreads();                 // WAR on hbuf/abuf from previous chunk
    // stage h0 (512 threads, 2 float4 each)
    {
      const float* src = pred + ((size_t)(kk*BB + b0))*HD;
      #pragma unroll
      for (int it=0; it<2; ++it){
        int u = tid + it*512;
        int row = u >> 5, c4 = (u & 31)*4;
        float4 v = *reinterpret_cast<const float4*>(src + row*HD + c4);
        int e = (row*HD + c4) ^ ((row&7)*8);
        *reinterpret_cast<uint32_t*>(&hbuf[e])   = pack2(v.x, v.y);
        *reinterpret_cast<uint32_t*>(&hbuf[e+2]) = pack2(v.z, v.w);
      }
    }
    __syncthreads();

    // ---- MLP GEMM1: [32,128] @ map_w0 -> [32,256]; 32 cols/wave ----
    {
      f32x4 acc1[2][2];
      #pragma unroll
      for (int ct=0; ct<2; ++ct){
        float mb = mb0[w*32 + ct*16 + ln];
        f32x4 v = {mb,mb,mb,mb};
        acc1[0][ct]=v; acc1[1][ct]=v;
      }
      #pragma unroll
      for (int q=0; q<4; ++q){
        bf16x8 af0 = ldh(hbuf, ln, q, p), af1 = ldh(hbuf, 16+ln, q, p);
        #pragma unroll
        for (int ct=0; ct<2; ++ct){
          bf16x8 wf;
          #pragma unroll
          for (int j=0; j<8; ++j)
            wf[j] = f2bf(mw0[(q*32+p*8+j)*MIDD + (w*32 + ct*16 + ln)]);
          acc1[0][ct] = mm(af0, wf, acc1[0][ct]);
          acc1[1][ct] = mm(af1, wf, acc1[1][ct]);
        }
      }
      #pragma unroll
      for (int rt=0; rt<2; ++rt)
      #pragma unroll
      for (int ct=0; ct<2; ++ct)
      #pragma unroll
      for (int r=0; r<4; ++r){
        float v = acc1[rt][ct][r];
        v = (v>0.f)? v : 0.01f*v;
        int row = rt*16 + p*4 + r;
        abuf[(row*MIDD + w*32 + ct*16 + ln) ^ ((row&7)*8)] = (uint16_t)f2bf(v);
      }
    }
    __syncthreads();

    // ---- MLP GEMM2: [32,256] @ map_w1 -> h_init; 16 cols/wave ----
    float c_[2][4];
    {
      f32x4 acc2[2];
      float mb = mb1[wofs + ln];
      f32x4 v = {mb,mb,mb,mb};
      acc2[0]=v; acc2[1]=v;
      #pragma unroll
      for (int q=0; q<8; ++q){
        bf16x8 af0 = lda(abuf, ln, q, p), af1 = lda(abuf, 16+ln, q, p);
        bf16x8 wf;
        #pragma unroll
        for (int j=0; j<8; ++j)
          wf[j] = f2bf(mw1[(q*32+p*8+j)*HD + wofs + ln]);
        acc2[0] = mm(af0, wf, acc2[0]);
        acc2[1] = mm(af1, wf, acc2[1]);
      }
      #pragma unroll
      for (int rt=0; rt<2; ++rt)
      #pragma unroll
      for (int r=0; r<4; ++r){
        int row = rt*16 + p*4 + r;
        hbuf[(row*HD + wofs + ln) ^ ((row&7)*8)] = (uint16_t)f2bf(acc2[rt][r]);
        c_[rt][r] = 0.f;
      }
    }
    __syncthreads();

    // ---- 12 recurrent steps ----
    #pragma unroll 1
    for (int t=0; t<OBS_LEN; ++t){
      // C-init = x@w_ih^T + (b_ih+b_hh), in D-layout
      f32x4 acc[2][4];
      #pragma unroll
      for (int rt=0; rt<2; ++rt){
        #pragma unroll
        for (int r=0; r<4; ++r){
          float2 xv = xbuf[t][rt*16 + p*4 + r];
          #pragma unroll
          for (int gate=0; gate<4; ++gate)
            acc[rt][gate][r] = fmaf(xv.x, wihA[gate], fmaf(xv.y, wihB[gate], biasv[gate]));
        }
      }
      f32x4 a8[2];
      if (w7 && t>0){ f32x4 v={obv,obv,obv,obv}; a8[0]=v; a8[1]=v; }
      #pragma unroll
      for (int q=0; q<4; ++q){
        bf16x8 af0 = ldh(hbuf, ln, q, p), af1 = ldh(hbuf, 16+ln, q, p);
        #pragma unroll
        for (int gate=0; gate<4; ++gate){
          acc[0][gate] = mm(af0, wfrag[gate][q], acc[0][gate]);
          acc[1][gate] = mm(af1, wfrag[gate][q], acc[1][gate]);
        }
        if (w7 && t>0){
          bf16x8 of = *reinterpret_cast<const bf16x8*>(&ofrag[(q*64 + l)*8]);
          a8[0] = mm(af0, of, a8[0]);
          a8[1] = mm(af1, of, a8[1]);
        }
      }
      if (w7 && t>0 && ln<NCQ){
        #pragma unroll
        for (int rt=0; rt<2; ++rt)
        #pragma unroll
        for (int r=0; r<4; ++r){
          int cell = rt*16 + p*4 + r;
          outp[(((size_t)(t-1)*KS + kk)*BB + b0 + cell)*NCQ + ln] = a8[rt][r];
        }
      }
      __syncthreads();               // all hbuf reads done
      #pragma unroll
      for (int rt=0; rt<2; ++rt)
      #pragma unroll
      for (int r=0; r<4; ++r){
        float iv = hsig(acc[rt][0][r]);
        float fv = hsig(acc[rt][1][r]);
        float gv = clip1(acc[rt][2][r]);
        float ov = hsig(acc[rt][3][r]);
        float cv = fmaf(fv, c_[rt][r], iv*gv);
        c_[rt][r] = cv;
        int row = rt*16 + p*4 + r;
        hbuf[(row*HD + wofs + ln) ^ ((row&7)*8)] = (uint16_t)f2bf(ov * clip1(cv));
      }
      __syncthreads();               // new h visible
    }

    // ---- final out_11 = h_12 @ out_w + out_b ----
    if (w7){
      f32x4 o0 = {obv,obv,obv,obv}, o1 = o0;
      #pragma unroll
      for (int q=0; q<4; ++q){
        bf16x8 af0 = ldh(hbuf, ln, q, p), af1 = ldh(hbuf, 16+ln, q, p);
        bf16x8 of = *reinterpret_cast<const bf16x8*>(&ofrag[(q*64 + l)*8]);
        o0 = mm(af0, of, o0);
        o1 = mm(af1, of, o1);
      }
      if (ln < NCQ){
        #pragma unroll
        for (int r=0; r<4; ++r){
          outp[(((size_t)11*KS + kk)*BB + b0 +      (p*4+r))*NCQ + ln] = o0[r];
          outp[(((size_t)11*KS + kk)*BB + b0 + 16 + (p*4+r))*NCQ + ln] = o1[r];
        }
      }
    }
  }
}

extern "C" void kernel_launch(void* const* d_in, const int* in_sizes, int n_in,
                              void* d_out, int out_size, void* d_ws, size_t ws_size,
                              hipStream_t stream) {
  (void)in_sizes; (void)n_in; (void)d_ws; (void)ws_size; (void)out_size;
  CRMF_35296041239144_kernel<<<dim3(256), dim3(512), 0, stream>>>(
      (const float*)d_in[0], (const float*)d_in[1], (const float*)d_in[2],
      (const float*)d_in[3], (const float*)d_in[4], (const float*)d_in[5],
      (const float*)d_in[6], (const float*)d_in[7], (const float*)d_in[8],
      (const float*)d_in[9], (const float*)d_in[10], (const float*)d_in[11],
      (float*)d_out);
}